// Round 14
// baseline (1206.026 us; speedup 1.0000x reference)
//
#include <hip/hip_runtime.h>
#include <hip/hip_bf16.h>
#include <math.h>

#define GH 721
#define GW 1440
#define C_IN 78
#define NNODES 5882
#define KNEIGH 128
#define M_TOTAL (NNODES * KNEIGH)   // 752896
#define TM 32
#define TILES 8
#define NBLOCKS (M_TOTAL / (TM * TILES))   // 2941

typedef __attribute__((ext_vector_type(8))) short bf16x8;
typedef __attribute__((ext_vector_type(4))) float f32x4;

// Raw s_barrier with explicit, minimal waitcnt fences. BAR_LGKM deliberately
// does NOT drain vmcnt: the in-flight global_load_lds DMA for tile t+1 must
// cross these barriers (a plain __syncthreads would serialize on it).
#define BAR_ALL()  do { asm volatile("s_waitcnt vmcnt(0) lgkmcnt(0)" ::: "memory"); \
                        __builtin_amdgcn_s_barrier(); } while (0)
#define BAR_LGKM() do { asm volatile("s_waitcnt lgkmcnt(0)" ::: "memory"); \
                        __builtin_amdgcn_s_barrier(); } while (0)

__device__ __forceinline__ unsigned short f2bf(float x) {
    __hip_bfloat16 b = __float2bfloat16(x);
    union { __hip_bfloat16 h; unsigned short u; } cv; cv.h = b; return cv.u;
}

// ---------------- prep kernel (unchanged from R11/R13) ----------------
__global__ void prep_kernel(const float* __restrict__ W1, const float* __restrict__ W2,
                            const float* __restrict__ means, const float* __restrict__ stds,
                            const float* __restrict__ b1, const float* __restrict__ lnS,
                            const float* __restrict__ lnO, const float* __restrict__ b2,
                            unsigned short* __restrict__ bp1, unsigned short* __restrict__ bp2,
                            float* __restrict__ latT, float* __restrict__ lonT,
                            float* __restrict__ b1p, float* __restrict__ K1,
                            float* __restrict__ K2)
{
    const int NB1 = 3 * 4 * 256 * 8;   // 24576
    const int NB2 = 8 * 4 * 256 * 8;   // 65536
    const int NTOT = NB1 + NB2 + GH + GW + 256;
    for (int e = blockIdx.x * blockDim.x + threadIdx.x; e < NTOT;
         e += gridDim.x * blockDim.x) {
        if (e < NB1) {
            int j = e & 7, c = (e >> 3) & 255, o = (e >> 11) & 3, s = e >> 13;
            int k = s * 32 + o * 8 + j;
            float v = 0.f;
            if (k < 82) v = W1[k * 256 + c] / (stds[k] + 1e-7f);
            bp1[e] = f2bf(v);
        } else if (e < NB1 + NB2) {
            int t = e - NB1;
            int j = t & 7, c = (t >> 3) & 255, o = (t >> 11) & 3, s = t >> 13;
            int k = s * 32 + o * 8 + j;
            bp2[t] = f2bf(W2[k * 256 + c] * lnS[k]);
        } else if (e < NB1 + NB2 + GH) {
            int h = e - NB1 - NB2;
            float r = (-90.f + 0.25f * (float)h) * 0.017453292519943295f;
            latT[2 * h]     = sinf(r);
            latT[2 * h + 1] = cosf(r);
        } else if (e < NB1 + NB2 + GH + GW) {
            int w = e - NB1 - NB2 - GH;
            float r = ((float)w * (360.f / 1439.f)) * 0.017453292519943295f;
            lonT[2 * w]     = sinf(r);
            lonT[2 * w + 1] = cosf(r);
        } else {
            int c = e - NB1 - NB2 - GH - GW;   // output/hidden column 0..255
            float acc = b1[c];
            #pragma unroll 1
            for (int k = 0; k < 86; ++k) {
                float inv = 1.f / (stds[k] + 1e-7f);
                float w = W1[k * 256 + c] * inv;
                acc -= means[k] * w;
                if (k == 82) acc += 0.5f * w;   // day-of-year channel, raw value 0.5
            }
            b1p[c] = acc;
            float k1 = 0.f, k2 = 0.f;
            #pragma unroll 1
            for (int k = 0; k < 256; ++k) {
                float w = W2[k * 256 + c];
                k1 += lnS[k] * w;
                k2 += lnO[k] * w;
            }
            K1[c] = k1;
            K2[c] = k2 + b2[c];
        }
    }
}

// ---------------- fused kernel: 8 tiles/block, DMA-pipelined gather ----------------
// Per tile: BAR_ALL (DMA(t) done) -> convert raw->x(bf16) -> issue DMA(t+1)
//           -> BAR_LGKM (DMA stays in flight) -> GEMM1 -> BAR_LGKM
//           -> ReLU/h/stats -> BAR_LGKM -> GEMM2 -> epilogue.
// Gather latency rides under a full tile of compute with ZERO registers held.
__global__ __launch_bounds__(256, 4)
void fused_kernel(const float* __restrict__ var_grid, const int* __restrict__ idxs,
                  const unsigned short* __restrict__ bp1, const unsigned short* __restrict__ bp2,
                  const float* __restrict__ latT, const float* __restrict__ lonT,
                  const float* __restrict__ b1p, const float* __restrict__ K1,
                  const float* __restrict__ K2,
                  float* __restrict__ out)
{
    __shared__ __align__(16) float raw[2][TM][C_IN];          // 19968 B DMA staging
    __shared__ __align__(16) unsigned short h_lds[TM * 256];  // 16384 B; x aliases front
    __shared__ float red[2][4][TM];                           // 1024 B stats partials
    unsigned short (*x_lds)[104] = (unsigned short (*)[104])h_lds;   // 6656 B

    // Bijective XCD-aware swizzle (nwg=2941, q=367, r=5)
    const int q_ = 367, r_ = 5;
    const int xcd = blockIdx.x & 7;
    const int ii  = blockIdx.x >> 3;
    const int swz = (xcd < r_ ? xcd * (q_ + 1) : r_ * (q_ + 1) + (xcd - r_) * q_) + ii;

    const int tid  = threadIdx.x;
    const int lane = tid & 63;
    const int wave = tid >> 6;       // 0..3
    const int wc   = wave;           // col quarter
    const int l15  = lane & 15;
    const int lg   = lane >> 4;      // 0..3
    const int wbase = wc * 64;
    const long block0 = (long)swz * (TM * TILES);

    const int crow = tid >> 3, cp = tid & 7;   // convert: 8 lanes/row

    // ---- DMA issue: 32 rows x 78 dwords = 2496 chunks, dense lane mapping ----
    auto dma_issue = [&](int t1) {
        const int buf = t1 & 1;
        #pragma unroll
        for (int i = 0; i < 10; ++i) {
            if (i < 9 || wave < 3) {           // 2496 = 9*256 + 192 (wave 3 skips i=9)
                const int cidx = i * 256 + tid;
                const int row  = cidx / 78;
                const int c    = cidx - row * 78;
                const int idx  = idxs[block0 + t1 * TM + row];
                const float* src = var_grid + (size_t)idx * C_IN + c;
                char* dst = ((char*)&raw[buf][0][0]) + (size_t)(i * 256 + wave * 64) * 4;
                __builtin_amdgcn_global_load_lds(
                    (const __attribute__((address_space(1))) void*)src,
                    (__attribute__((address_space(3))) void*)dst, 4, 0, 0);
            }
        }
    };

    dma_issue(0);

    float b1v[4];
    #pragma unroll
    for (int nf = 0; nf < 4; ++nf) b1v[nf] = b1p[wbase + nf * 16 + l15];

    #pragma unroll 1
    for (int t = 0; t < TILES; ++t) {
        BAR_ALL();   // DMA(t) complete + visible; h/x region free (GEMM2(t-1) done)

        // ---- convert: raw f32 -> x bf16 (stride 104), tails from tables ----
        {
            const float* rr = &raw[t & 1][crow][0];
            const int idx = idxs[block0 + t * TM + crow];   // L2-hot line
            unsigned int* xrow = (unsigned int*)&x_lds[crow][0];
            float tv0 = 0.f, tv1 = 0.f, tw0 = 0.f, tw1 = 0.f;
            if (cp == 7) {                     // q=39: lat sin/cos
                int hh = idx / GW;
                tv0 = latT[2 * hh]; tv1 = latT[2 * hh + 1];
            }
            if (cp == 0) {                     // q=40: lon sin/cos
                int hh = idx / GW;
                int ww = idx - hh * GW;
                tw0 = lonT[2 * ww]; tw1 = lonT[2 * ww + 1];
            }
            #pragma unroll
            for (int u = 0; u < 6; ++u) {
                const int q = cp + 8 * u;      // channels 2q, 2q+1
                float v0, v1;
                if (q <= 38)      { float2 g = *(const float2*)(rr + 2 * q); v0 = g.x; v1 = g.y; }
                else if (q == 39) { v0 = tv0; v1 = tv1; }
                else if (q == 40) { v0 = tw0; v1 = tw1; }
                else              { v0 = 0.f; v1 = 0.f; }   // ch 82..95 folded / pad
                xrow[q] = ((unsigned int)f2bf(v1) << 16) | (unsigned int)f2bf(v0);
            }
        }

        if (t + 1 < TILES) dma_issue(t + 1);   // flies under GEMM1+GEMM2 of tile t

        BAR_LGKM();   // x ready; DMA(t+1) NOT drained

        // ---- GEMM1: x[32x96] @ W1'[96x256] ----
        f32x4 acc[2][4];
        #pragma unroll
        for (int mf = 0; mf < 2; ++mf)
            #pragma unroll
            for (int nf = 0; nf < 4; ++nf) acc[mf][nf] = (f32x4){0.f, 0.f, 0.f, 0.f};

        #pragma unroll
        for (int s = 0; s < 3; ++s) {
            bf16x8 af[2], bw[4];
            #pragma unroll
            for (int nf = 0; nf < 4; ++nf)
                bw[nf] = *(const bf16x8*)(bp1 + ((size_t)((s * 4 + lg) * 256) + wbase + nf * 16 + l15) * 8);
            #pragma unroll
            for (int mf = 0; mf < 2; ++mf)
                af[mf] = *(const bf16x8*)&x_lds[mf * 16 + l15][s * 32 + lg * 8];
            #pragma unroll
            for (int mf = 0; mf < 2; ++mf)
                #pragma unroll
                for (int nf = 0; nf < 4; ++nf)
                    acc[mf][nf] = __builtin_amdgcn_mfma_f32_16x16x32_bf16(af[mf], bw[nf], acc[mf][nf], 0, 0, 0);
        }

        BAR_LGKM();   // all x reads done -> h writes (same region) safe

        // ---- bias + ReLU -> h (bf16, swizzled) + row-stat partials ----
        float sm[2][4], sq[2][4];
        #pragma unroll
        for (int mf = 0; mf < 2; ++mf)
            #pragma unroll
            for (int i = 0; i < 4; ++i) { sm[mf][i] = 0.f; sq[mf][i] = 0.f; }

        #pragma unroll
        for (int mf = 0; mf < 2; ++mf)
            #pragma unroll
            for (int nf = 0; nf < 4; ++nf)
                #pragma unroll
                for (int i = 0; i < 4; ++i) {
                    float v = fmaxf(acc[mf][nf][i] + b1v[nf], 0.f);
                    sm[mf][i] += v;
                    sq[mf][i] += v * v;
                    int row = mf * 16 + lg * 4 + i;
                    int col = wbase + nf * 16 + l15;
                    unsigned off = (unsigned)(row * 512 + col * 2);
                    off ^= (unsigned)((row & 7) << 4);
                    *(unsigned short*)((char*)h_lds + off) = f2bf(v);
                }

        #pragma unroll
        for (int m = 1; m < 16; m <<= 1)
            #pragma unroll
            for (int mf = 0; mf < 2; ++mf)
                #pragma unroll
                for (int i = 0; i < 4; ++i) {
                    sm[mf][i] += __shfl_xor(sm[mf][i], m, 64);
                    sq[mf][i] += __shfl_xor(sq[mf][i], m, 64);
                }

        if (l15 == 0) {
            #pragma unroll
            for (int mf = 0; mf < 2; ++mf)
                #pragma unroll
                for (int i = 0; i < 4; ++i) {
                    int row = mf * 16 + lg * 4 + i;
                    red[0][wc][row] = sm[mf][i];
                    red[1][wc][row] = sq[mf][i];
                }
        }

        BAR_LGKM();   // h + red visible

        // ---- GEMM2: h[32x256] @ W2'[256x256] ----
        #pragma unroll
        for (int mf = 0; mf < 2; ++mf)
            #pragma unroll
            for (int nf = 0; nf < 4; ++nf) acc[mf][nf] = (f32x4){0.f, 0.f, 0.f, 0.f};

        #pragma unroll
        for (int s = 0; s < 8; ++s) {
            bf16x8 af[2], bw[4];
            #pragma unroll
            for (int nf = 0; nf < 4; ++nf)
                bw[nf] = *(const bf16x8*)(bp2 + ((size_t)((s * 4 + lg) * 256) + wbase + nf * 16 + l15) * 8);
            #pragma unroll
            for (int mf = 0; mf < 2; ++mf) {
                int row = mf * 16 + l15;
                unsigned off = (unsigned)(row * 512 + (s * 32 + lg * 8) * 2);
                off ^= (unsigned)((row & 7) << 4);
                af[mf] = *(const bf16x8*)((char*)h_lds + off);
            }
            #pragma unroll
            for (int mf = 0; mf < 2; ++mf)
                #pragma unroll
                for (int nf = 0; nf < 4; ++nf)
                    acc[mf][nf] = __builtin_amdgcn_mfma_f32_16x16x32_bf16(af[mf], bw[nf], acc[mf][nf], 0, 0, 0);
        }

        // ---- epilogue: LN algebraic; direct plain stores ----
        float K1v[4], K2v[4];
        #pragma unroll
        for (int nf = 0; nf < 4; ++nf) {
            int col = wbase + nf * 16 + l15;
            K1v[nf] = K1[col]; K2v[nf] = K2[col];
        }
        #pragma unroll
        for (int mf = 0; mf < 2; ++mf)
            #pragma unroll
            for (int i = 0; i < 4; ++i) {
                int row = mf * 16 + lg * 4 + i;
                float tot = red[0][0][row] + red[0][1][row] + red[0][2][row] + red[0][3][row];
                float tq  = red[1][0][row] + red[1][1][row] + red[1][2][row] + red[1][3][row];
                float mean = tot * (1.f / 256.f);
                float var  = tq * (1.f / 256.f) - mean * mean;
                float rs = rsqrtf(var + 1e-5f);
                long row_g = block0 + t * TM + row;
                float* po = out + row_g * 256 + wbase;
                #pragma unroll
                for (int nf = 0; nf < 4; ++nf)
                    po[nf * 16 + l15] = rs * (acc[mf][nf][i] - mean * K1v[nf]) + K2v[nf];
            }
    }
}

extern "C" void kernel_launch(void* const* d_in, const int* in_sizes, int n_in,
                              void* d_out, int out_size, void* d_ws, size_t ws_size,
                              hipStream_t stream) {
    const float* var_grid = (const float*)d_in[0];
    const int*   idxs     = (const int*)d_in[1];
    const float* means    = (const float*)d_in[2];
    const float* stds     = (const float*)d_in[3];
    const float* W1       = (const float*)d_in[4];
    const float* b1       = (const float*)d_in[5];
    const float* lnS      = (const float*)d_in[6];
    const float* lnO      = (const float*)d_in[7];
    const float* W2       = (const float*)d_in[8];
    const float* b2       = (const float*)d_in[9];
    float* out = (float*)d_out;

    char* ws = (char*)d_ws;
    unsigned short* bp1 = (unsigned short*)ws;               // 49152 B
    unsigned short* bp2 = (unsigned short*)(ws + 49152);     // 131072 B -> 180224
    float* latT = (float*)(ws + 180224);                     // 5768 B
    float* lonT = (float*)(ws + 186000);                     // 11520 B
    float* b1p  = (float*)(ws + 197520);                     // 1024 B
    float* K1   = (float*)(ws + 198544);                     // 1024 B
    float* K2   = (float*)(ws + 199568);                     // 1024 B (end 200592)

    prep_kernel<<<362, 256, 0, stream>>>(W1, W2, means, stds, b1, lnS, lnO, b2,
                                         bp1, bp2, latT, lonT, b1p, K1, K2);
    fused_kernel<<<NBLOCKS, 256, 0, stream>>>(var_grid, idxs, bp1, bp2, latT, lonT,
                                              b1p, K1, K2, out);
}